// Round 10
// baseline (124.459 us; speedup 1.0000x reference)
//
#include <hip/hip_runtime.h>

typedef unsigned short u16;
typedef unsigned int   u32;

typedef __attribute__((ext_vector_type(8))) short short8;
typedef __attribute__((ext_vector_type(4))) float floatx4;
typedef __attribute__((ext_vector_type(2))) float v2f;

// ---- f32 -> bf16 (RNE) ----
__device__ __forceinline__ u16 f2bf(float f) {
    u32 u = __float_as_uint(f);
    u = u + 0x7fffu + ((u >> 16) & 1u);
    return (u16)(u >> 16);
}

// pack two f32 -> two bf16 (round-to-nearest-away) in one v_perm
__device__ __forceinline__ u32 pack2bf(float s0, float s1) {
    u32 a = __float_as_uint(s0) + 0x8000u;
    u32 b = __float_as_uint(s1) + 0x8000u;
    return __builtin_amdgcn_perm(b, a, 0x07060302u);  // {b.hi16, a.hi16}
}

__device__ __forceinline__ floatx4 mfma16(short8 a, short8 b, floatx4 c) {
    return __builtin_amdgcn_mfma_f32_16x16x32_bf16(a, b, c, 0, 0, 0);
}

// ---- prep: SoA x copy + per-thread B-fragment streams (scatter form, r5/r6) +
// output zeroing. Source reads coalesced, scattered 2B/4B writes.
// xsoa:  [b][comp][n]  (16 x 3 x 2048 f32) -- scalar-path source for k_fused gen
// W1frag: [kt*8192 + t*16 + j*8 + ji] = bf16(W1[(7+kt*32+lq*8+ji)*256 + w*32+j*16+lr])
// W2frag: same form over W2
// W3frag: [kt*4096 + t*8 + ji]       = bf16(W3[(kt*32+lq*8+ji)*128 + w*16+lr])
__global__ void k_prep(const float* __restrict__ x, const float* __restrict__ W1,
                       const float* __restrict__ W2, const float* __restrict__ W3,
                       float* __restrict__ xsoa, u16* __restrict__ W1frag,
                       u16* __restrict__ W2frag, u16* __restrict__ W3frag,
                       float* __restrict__ out) {
    int idx = blockIdx.x * 256 + threadIdx.x;
    if (idx < 6144) out[idx] = 0.f;
    if (idx < 98304) {
        int b = idx / 6144, r = idx - b * 6144;
        int comp = r >> 11, n = r & 2047;
        xsoa[idx] = x[(b * 2048 + n) * 3 + comp];   // write coalesced
    } else if (idx < 622592) {
        int i = idx - 98304;
        int row = i >> 8, c = i & 255;              // W1 row-7, col
        float v = W1[1792 + i];                     // coalesced
        int kt = row >> 5, rr = row & 31;
        int lq = rr >> 3, ji = rr & 7;
        int w = c >> 5, cc = c & 31;
        int j = cc >> 4, lr = cc & 15;
        W1frag[kt * 8192 + (w * 64 + lq * 16 + lr) * 16 + j * 8 + ji] = f2bf(v);
    } else if (idx < 688128) {
        int i = idx - 622592;
        int row = i >> 8, c = i & 255;
        float v = W2[i];                            // coalesced
        int kt = row >> 5, rr = row & 31;
        int lq = rr >> 3, ji = rr & 7;
        int w = c >> 5, cc = c & 31;
        int j = cc >> 4, lr = cc & 15;
        W2frag[kt * 8192 + (w * 64 + lq * 16 + lr) * 16 + j * 8 + ji] = f2bf(v);
    } else if (idx < 720896) {
        int i = idx - 688128;
        int row = i >> 7, c = i & 127;
        float v = W3[i];                            // coalesced
        int kt = row >> 5, rr = row & 31;
        int lq = rr >> 3, ji = rr & 7;
        int w = c >> 4, lr = c & 15;
        W3frag[kt * 4096 + (w * 64 + lq * 16 + lr) * 8 + ji] = f2bf(v);
    }
}

// ---- fully fused: h1 (dots GEMM) -> h2 -> fk -> x-reduce, one block per 64 rows.
// 512 threads (8 waves), 1M x 8N wave layout (r5-proven liveness), K=64
// superstep, swizzled As (conflict-free, r2/r3), colsml LDS staging (r4/r5).
// Round-10 (r9 post-mortem: gen LOAD latency sits on the per-superstep critical
// path): T14 issue-early/consume-late split at distance 1 -- at ss s the store
// for s+1 computes from registers loaded during ss s-1 (gen_load(s+2) issues
// right after), so the ~300cy scalar-load latency spans a full superstep
// instead of stalling the chain. 6 float4 staging regs (uniform address ->
// scalar path; VGPR headroom 64/128 regardless). Everything else == r9.
// r8 lesson kept: xsm overlay (inside As buf1) written AFTER the main loop.
// LDS map (76288 B, 2 blocks/CU):
//   [24576,40960) main: As u16[2][64][64] swizzled dots tile
//     tail overlay (after loop): h1s u16[64][264] @0 | xsm @33792 | redm @34816
//   [40960,42496) rowsml f32[64][6]
//   [42496,76288) h2s u16[64][264] (phase 1+)
//     start/epilogue overlay: colsml f32[256][8] @42496 -- read into regs
//     BEFORE the barrier that precedes h2s writes.
__global__ __launch_bounds__(512, 4) void k_fused(
    const float* __restrict__ xsoa, const float* __restrict__ u,
    const float* __restrict__ basis, const float* __restrict__ W1,
    const float* __restrict__ b1, const float* __restrict__ b2,
    const float* __restrict__ b3, const u16* __restrict__ W1frag,
    const u16* __restrict__ W2frag, const u16* __restrict__ W3frag,
    float* __restrict__ out) {
    __shared__ __align__(16) char smem[76288];
    char* Asb = smem + 24576;                        // swizzled dots tile
    u16 (*h1s)[264] = (u16(*)[264])smem;             // tail overlay
    float (*xsm)[4] = (float(*)[4])(smem + 33792);
    float (*redm)[4] = (float(*)[4])(smem + 34816);
    float (*rowsml)[6] = (float(*)[6])(smem + 40960);
    float (*colsml)[8] = (float(*)[8])(smem + 42496);
    u16 (*h2s)[264] = (u16(*)[264])(smem + 42496);

    const int t = threadIdx.x;
    const int b = blockIdx.y;
    const int i0 = blockIdx.x * 64;
    const int lane = t & 63, w = t >> 6;
    const int lr = lane & 15, lq = lane >> 4;

    const float* Xg = xsoa + b * 6144;               // [X 2048][Y 2048][Z 2048]
    const float ax = Xg[i0 + lane];                  // coalesced, one-time
    const float ay = Xg[2048 + i0 + lane];
    const float az = Xg[4096 + i0 + lane];

    // stage ALL small per-column constants into LDS (r3-proven; kills hoisting)
    if (t < 256) {
        int c = t;
        float u0 = u[b * 2 + 0], u1 = u[b * 2 + 1];
        colsml[c][0] = b1[c] + u0 * W1[c] + u1 * W1[256 + c];
        colsml[c][1] = W1[512 + c];
        colsml[c][2] = W1[768 + c];
        colsml[c][3] = W1[1024 + c];
        colsml[c][4] = W1[1280 + c];
        colsml[c][5] = W1[1536 + c];
        colsml[c][6] = b2[c];
        if (c < 128) colsml[c][7] = b3[c];
    }
    if (t < 64) {
        rowsml[t][0] = sqrtf(ax * ax + ay * ay + az * az);  // lane==t here
#pragma unroll
        for (int p = 0; p < 4; ++p) {
            const float* bp = basis + (b * 4 + p) * 3;
            rowsml[t][1 + p] = ax * bp[0] + ay * bp[1] + az * bp[2];
        }
    }

    // swizzled LDS addressing (all loop-invariant); conflict-free (r2/r3)
    char* aswp = Asb + lane * 128 + ((w ^ (lane & 7)) << 4);   // write ptr, buf0
    int ro[4];
    {
        int sl = (lq ^ (lr & 7));
#pragma unroll
        for (int i = 0; i < 4; ++i)
            ro[i] = (i * 16 + lr) * 128 + (sl << 4);           // kk=0; kk=1 is ^64
    }

    // ---- gen split (T14): load stage (uniform scalar-path, issued 1 ss early)
    struct XR { float4 x0, x1, y0, y1, z0, z1; };
    auto gen_load = [&](int s) {
        int c0u = __builtin_amdgcn_readfirstlane(s * 64 + w * 8);
        const float* Xc = Xg + c0u;
        XR r;
        r.x0 = *(const float4*)(Xc);        r.x1 = *(const float4*)(Xc + 4);
        r.y0 = *(const float4*)(Xc + 2048); r.y1 = *(const float4*)(Xc + 2052);
        r.z0 = *(const float4*)(Xc + 4096); r.z1 = *(const float4*)(Xc + 4100);
        return r;
    };
    // compute+store stage: 8 dots from staged regs -> As[buf] (swizzled b128)
    auto gen_cs = [&](const XR& rg, int buf) {
        v2f dA, dB, dC, dD;
        {
            v2f t0 = {rg.x0.x, rg.x0.y}, t1 = {rg.x0.z, rg.x0.w};
            v2f t2 = {rg.x1.x, rg.x1.y}, t3 = {rg.x1.z, rg.x1.w};
            dA = t0 * ax; dB = t1 * ax; dC = t2 * ax; dD = t3 * ax;
        }
        {
            v2f t0 = {rg.y0.x, rg.y0.y}, t1 = {rg.y0.z, rg.y0.w};
            v2f t2 = {rg.y1.x, rg.y1.y}, t3 = {rg.y1.z, rg.y1.w};
            dA += t0 * ay; dB += t1 * ay; dC += t2 * ay; dD += t3 * ay;
        }
        {
            v2f t0 = {rg.z0.x, rg.z0.y}, t1 = {rg.z0.z, rg.z0.w};
            v2f t2 = {rg.z1.x, rg.z1.y}, t3 = {rg.z1.z, rg.z1.w};
            dA += t0 * az; dB += t1 * az; dC += t2 * az; dD += t3 * az;
        }
        float s0 = __builtin_amdgcn_sqrtf(dA.x);
        float s1 = __builtin_amdgcn_sqrtf(dA.y);
        float s2 = __builtin_amdgcn_sqrtf(dB.x);
        float s3 = __builtin_amdgcn_sqrtf(dB.y);
        float s4 = __builtin_amdgcn_sqrtf(dC.x);
        float s5 = __builtin_amdgcn_sqrtf(dC.y);
        float s6 = __builtin_amdgcn_sqrtf(dD.x);
        float s7 = __builtin_amdgcn_sqrtf(dD.y);
        uint4 dv;
        dv.x = pack2bf(s0, s1); dv.y = pack2bf(s2, s3);
        dv.z = pack2bf(s4, s5); dv.w = pack2bf(s6, s7);
        *(uint4*)(aswp + buf * 8192) = dv;
    };

    floatx4 acc[4][2];
    const floatx4 zero = {0.f, 0.f, 0.f, 0.f};
#pragma unroll
    for (int i = 0; i < 4; ++i)
#pragma unroll
        for (int j = 0; j < 2; ++j) acc[i][j] = zero;

    // prologue: gen(0) inline (latency OK here), stage loads for ss 1
    {
        XR r0 = gen_load(0);
        gen_cs(r0, 0);
    }
    XR R = gen_load(1);
    __syncthreads();

    {
        const u16* wf = W1frag + t * 16;
        short8 a[4], bfr[4];
#pragma unroll 2
        for (int s = 0; s < 32; ++s) {
            const int buf = s & 1;
            const u16* wb = wf + (2 * s) * 8192;   // L2-hot B stream
            bfr[0] = *(const short8*)(wb);
            bfr[1] = *(const short8*)(wb + 8);
            bfr[2] = *(const short8*)(wb + 8192);
            bfr[3] = *(const short8*)(wb + 8192 + 8);
            // A kk=0
#pragma unroll
            for (int i = 0; i < 4; ++i)
                a[i] = *(const short8*)(Asb + buf * 8192 + ro[i]);
            // dots for s+1 from regs staged at s-1; then issue loads for s+2
            if (s < 31) gen_cs(R, buf ^ 1);
            if (s < 30) R = gen_load(s + 2);
#pragma unroll
            for (int i = 0; i < 4; ++i)
#pragma unroll
                for (int j = 0; j < 2; ++j)
                    acc[i][j] = mfma16(a[i], bfr[j], acc[i][j]);
            // A kk=1 (same buffer; reads hide under other waves' MFMA issue)
#pragma unroll
            for (int i = 0; i < 4; ++i)
                a[i] = *(const short8*)(Asb + buf * 8192 + (ro[i] ^ 64));
#pragma unroll
            for (int i = 0; i < 4; ++i)
#pragma unroll
                for (int j = 0; j < 2; ++j)
                    acc[i][j] = mfma16(a[i], bfr[2 + j], acc[i][j]);
            __syncthreads();
        }
    }

    // ---- epilogue: h1 = small features + bias, LeakyReLU -> h1s (LDS bf16)
    // As is dead now; xsm overlay (inside As buf1 range) is safe to write HERE.
    if (t < 64) { xsm[t][0] = ax; xsm[t][1] = ay; xsm[t][2] = az; }
    const int c0 = w * 32 + lr, c1 = c0 + 16;
    const int c3 = w * 16 + lr;
    float cb0, cb1, cb3;   // b2/b3 pulled from colsml BEFORE h2s overwrites it
    {
        float c0v[7], c1v[7];
#pragma unroll
        for (int q = 0; q < 7; ++q) { c0v[q] = colsml[c0][q]; c1v[q] = colsml[c1][q]; }
        cb0 = c0v[6]; cb1 = c1v[6];
        cb3 = colsml[c3][7];
#pragma unroll
        for (int i = 0; i < 4; ++i) {
#pragma unroll
            for (int r = 0; r < 4; ++r) {
                int row = i * 16 + lq * 4 + r;
                float nrm = rowsml[row][0];
                float p0 = rowsml[row][1], p1 = rowsml[row][2];
                float p2 = rowsml[row][3], p3 = rowsml[row][4];
                float v0 = acc[i][0][r] + c0v[0] + nrm * c0v[1] +
                           p0 * c0v[2] + p1 * c0v[3] + p2 * c0v[4] + p3 * c0v[5];
                v0 = v0 > 0.f ? v0 : 0.01f * v0;
                h1s[row][c0] = f2bf(v0);
                float v1 = acc[i][1][r] + c1v[0] + nrm * c1v[1] +
                           p0 * c1v[2] + p1 * c1v[3] + p2 * c1v[4] + p3 * c1v[5];
                v1 = v1 > 0.f ? v1 : 0.01f * v1;
                h1s[row][c1] = f2bf(v1);
            }
        }
    }
    __syncthreads();

    // ---- phase 1: h2 = lrelu(h1s @ W2 + b2) -> h2s (overwrites colsml; safe)
#pragma unroll
    for (int i = 0; i < 4; ++i)
#pragma unroll
        for (int j = 0; j < 2; ++j) acc[i][j] = zero;
    {
        const u16* w2s = W2frag + t * 16;
#pragma unroll 2
        for (int kt = 0; kt < 8; ++kt) {
            short8 af[4], bfr[2];
#pragma unroll
            for (int i = 0; i < 4; ++i)
                af[i] = *(const short8*)&h1s[i * 16 + lr][kt * 32 + lq * 8];
#pragma unroll
            for (int j = 0; j < 2; ++j)
                bfr[j] = *(const short8*)(w2s + kt * 8192 + j * 8);
#pragma unroll
            for (int i = 0; i < 4; ++i)
#pragma unroll
                for (int j = 0; j < 2; ++j)
                    acc[i][j] = mfma16(af[i], bfr[j], acc[i][j]);
        }
#pragma unroll
        for (int i = 0; i < 4; ++i)
#pragma unroll
            for (int r = 0; r < 4; ++r) {
                int row = i * 16 + lq * 4 + r;
                float v0 = acc[i][0][r] + cb0;
                v0 = v0 > 0.f ? v0 : 0.01f * v0;
                h2s[row][c0] = f2bf(v0);
                float v1 = acc[i][1][r] + cb1;
                v1 = v1 > 0.f ? v1 : 0.01f * v1;
                h2s[row][c1] = f2bf(v1);
            }
    }
    __syncthreads();

    // ---- phase 2: fk = h2s @ W3 + b3, fused x outer-product reduce
    {
        floatx4 acc2[4];
#pragma unroll
        for (int i = 0; i < 4; ++i) acc2[i] = zero;
        const u16* w3s = W3frag + t * 8;
#pragma unroll 2
        for (int kt = 0; kt < 8; ++kt) {
            short8 af[4];
#pragma unroll
            for (int i = 0; i < 4; ++i)
                af[i] = *(const short8*)&h2s[i * 16 + lr][kt * 32 + lq * 8];
            short8 bfr = *(const short8*)(w3s + kt * 4096);
#pragma unroll
            for (int i = 0; i < 4; ++i) acc2[i] = mfma16(af[i], bfr, acc2[i]);
        }
        float s0 = 0.f, s1 = 0.f, s2 = 0.f;
#pragma unroll
        for (int i = 0; i < 4; ++i)
#pragma unroll
            for (int r = 0; r < 4; ++r) {
                int row = i * 16 + lq * 4 + r;
                float fk = acc2[i][r] + cb3;
                s0 += fk * xsm[row][0];
                s1 += fk * xsm[row][1];
                s2 += fk * xsm[row][2];
            }
        s0 += __shfl_xor(s0, 16); s0 += __shfl_xor(s0, 32);
        s1 += __shfl_xor(s1, 16); s1 += __shfl_xor(s1, 32);
        s2 += __shfl_xor(s2, 16); s2 += __shfl_xor(s2, 32);
        if (lq == 0) {  // lanes 0..15; cols wave-exclusive
            redm[c3][0] = s0; redm[c3][1] = s1; redm[c3][2] = s2;
        }
    }
    __syncthreads();
    if (t < 128) {
#pragma unroll
        for (int d = 0; d < 3; ++d)
            atomicAdd(&out[(b * 128 + t) * 3 + d], redm[t][d] * (1.0f / 2048.0f));
    }
}

extern "C" void kernel_launch(void* const* d_in, const int* in_sizes, int n_in,
                              void* d_out, int out_size, void* d_ws, size_t ws_size,
                              hipStream_t stream) {
    const float* x     = (const float*)d_in[0];
    const float* u     = (const float*)d_in[1];
    const float* basis = (const float*)d_in[2];
    const float* W1    = (const float*)d_in[3];
    const float* b1    = (const float*)d_in[4];
    const float* W2    = (const float*)d_in[5];
    const float* b2    = (const float*)d_in[6];
    const float* W3    = (const float*)d_in[7];
    const float* b3    = (const float*)d_in[8];
    float* out = (float*)d_out;

    char* ws = (char*)d_ws;
    u16*  W1frag = (u16*)ws;                      // 1,048,576 B
    u16*  W2frag = (u16*)(ws + 1048576);          //   131,072 B
    u16*  W3frag = (u16*)(ws + 1179648);          //    65,536 B
    float* xsoa  = (float*)(ws + 1245184);        //   393,216 B

    k_prep<<<2816, 256, 0, stream>>>(x, W1, W2, W3, xsoa, W1frag, W2frag,
                                     W3frag, out);
    k_fused<<<dim3(32, 16), 512, 0, stream>>>(xsoa, u, basis, W1, b1, b2, b3,
                                              W1frag, W2frag, W3frag, out);
}

// Round 11
// 121.413 us; speedup vs baseline: 1.0251x; 1.0251x over previous
//
#include <hip/hip_runtime.h>

typedef unsigned short u16;
typedef unsigned int   u32;

typedef __attribute__((ext_vector_type(8))) short short8;
typedef __attribute__((ext_vector_type(4))) float floatx4;
typedef __attribute__((ext_vector_type(2))) float v2f;

// ---- f32 -> bf16 (RNE) ----
__device__ __forceinline__ u16 f2bf(float f) {
    u32 u = __float_as_uint(f);
    u = u + 0x7fffu + ((u >> 16) & 1u);
    return (u16)(u >> 16);
}

// pack two f32 -> two bf16 (round-to-nearest-away) in one v_perm
__device__ __forceinline__ u32 pack2bf(float s0, float s1) {
    u32 a = __float_as_uint(s0) + 0x8000u;
    u32 b = __float_as_uint(s1) + 0x8000u;
    return __builtin_amdgcn_perm(b, a, 0x07060302u);  // {b.hi16, a.hi16}
}

__device__ __forceinline__ floatx4 mfma16(short8 a, short8 b, floatx4 c) {
    return __builtin_amdgcn_mfma_f32_16x16x32_bf16(a, b, c, 0, 0, 0);
}

// ---- prep: SoA x copy + per-thread B-fragment streams (scatter form, r5/r6) +
// output zeroing. Source reads coalesced, scattered 2B/4B writes.
// xsoa:  [b][comp][n]  (16 x 3 x 2048 f32) -- scalar-path source for k_fused gen
// W1frag: [kt*8192 + t*16 + j*8 + ji] = bf16(W1[(7+kt*32+lq*8+ji)*256 + w*32+j*16+lr])
// W2frag: same form over W2
// W3frag: [kt*4096 + t*8 + ji]       = bf16(W3[(kt*32+lq*8+ji)*128 + w*16+lr])
__global__ void k_prep(const float* __restrict__ x, const float* __restrict__ W1,
                       const float* __restrict__ W2, const float* __restrict__ W3,
                       float* __restrict__ xsoa, u16* __restrict__ W1frag,
                       u16* __restrict__ W2frag, u16* __restrict__ W3frag,
                       float* __restrict__ out) {
    int idx = blockIdx.x * 256 + threadIdx.x;
    if (idx < 6144) out[idx] = 0.f;
    if (idx < 98304) {
        int b = idx / 6144, r = idx - b * 6144;
        int comp = r >> 11, n = r & 2047;
        xsoa[idx] = x[(b * 2048 + n) * 3 + comp];   // write coalesced
    } else if (idx < 622592) {
        int i = idx - 98304;
        int row = i >> 8, c = i & 255;              // W1 row-7, col
        float v = W1[1792 + i];                     // coalesced
        int kt = row >> 5, rr = row & 31;
        int lq = rr >> 3, ji = rr & 7;
        int w = c >> 5, cc = c & 31;
        int j = cc >> 4, lr = cc & 15;
        W1frag[kt * 8192 + (w * 64 + lq * 16 + lr) * 16 + j * 8 + ji] = f2bf(v);
    } else if (idx < 688128) {
        int i = idx - 622592;
        int row = i >> 8, c = i & 255;
        float v = W2[i];                            // coalesced
        int kt = row >> 5, rr = row & 31;
        int lq = rr >> 3, ji = rr & 7;
        int w = c >> 5, cc = c & 31;
        int j = cc >> 4, lr = cc & 15;
        W2frag[kt * 8192 + (w * 64 + lq * 16 + lr) * 16 + j * 8 + ji] = f2bf(v);
    } else if (idx < 720896) {
        int i = idx - 688128;
        int row = i >> 7, c = i & 127;
        float v = W3[i];                            // coalesced
        int kt = row >> 5, rr = row & 31;
        int lq = rr >> 3, ji = rr & 7;
        int w = c >> 4, lr = c & 15;
        W3frag[kt * 4096 + (w * 64 + lq * 16 + lr) * 8 + ji] = f2bf(v);
    }
}

// ---- fully fused: h1 (dots GEMM) -> h2 -> fk -> x-reduce, one block per 64 rows.
// 512 threads (8 waves), 1M x 8N wave layout (r5-proven liveness), K=64
// superstep, swizzled As (conflict-free, r2/r3), colsml LDS staging (r4/r5),
// T14 gen load/compute split (r10).
// Round-11: 4-deep As ring in the LDS freed by r9 ([0,32768), 4 x 8 KB) with
// ONE BARRIER PER 2 SUPERSTEPS (16 total, was 32). Epoch {2e,2e+1} reads bufs
// {2e&3,(2e+1)&3} and writes {(2e+2)&3,(2e+3)&3} -- disjoint ring halves, so
// the <=1-ss intra-epoch wave drift cannot race reads vs writes. Gen runs at
// distance 2: at ss s, gen_cs(R -> buf (s+2)&3) from regs loaded at ss s-1,
// then R = gen_load(s+3) (T14 window still >= 1 full superstep).
// r8 lesson kept: tail overlays written only AFTER the main loop's last barrier.
// LDS map (76288 B, 2 blocks/CU):
//   [0,32768)     main: As u16[4][64][64] ring (swizzled dots tiles)
//     tail overlay (after loop): h1s u16[64][264] @0
//   [33792,34816) xsm f32[64][4] (tail; dead space during main loop)
//   [34816,36864) redm f32[128][4] (tail)
//   [40960,42496) rowsml f32[64][6]
//   [42496,76288) h2s u16[64][264] (phase 1+)
//     start/epilogue overlay: colsml f32[256][8] @42496 -- read into regs
//     BEFORE the barrier that precedes h2s writes.
__global__ __launch_bounds__(512, 4) void k_fused(
    const float* __restrict__ xsoa, const float* __restrict__ u,
    const float* __restrict__ basis, const float* __restrict__ W1,
    const float* __restrict__ b1, const float* __restrict__ b2,
    const float* __restrict__ b3, const u16* __restrict__ W1frag,
    const u16* __restrict__ W2frag, const u16* __restrict__ W3frag,
    float* __restrict__ out) {
    __shared__ __align__(16) char smem[76288];
    char* Asb = smem;                                // 4-deep swizzled dots ring
    u16 (*h1s)[264] = (u16(*)[264])smem;             // tail overlay
    float (*xsm)[4] = (float(*)[4])(smem + 33792);
    float (*redm)[4] = (float(*)[4])(smem + 34816);
    float (*rowsml)[6] = (float(*)[6])(smem + 40960);
    float (*colsml)[8] = (float(*)[8])(smem + 42496);
    u16 (*h2s)[264] = (u16(*)[264])(smem + 42496);

    const int t = threadIdx.x;
    const int b = blockIdx.y;
    const int i0 = blockIdx.x * 64;
    const int lane = t & 63, w = t >> 6;
    const int lr = lane & 15, lq = lane >> 4;

    const float* Xg = xsoa + b * 6144;               // [X 2048][Y 2048][Z 2048]
    const float ax = Xg[i0 + lane];                  // coalesced, one-time
    const float ay = Xg[2048 + i0 + lane];
    const float az = Xg[4096 + i0 + lane];

    // stage ALL small per-column constants into LDS (r3-proven; kills hoisting)
    if (t < 256) {
        int c = t;
        float u0 = u[b * 2 + 0], u1 = u[b * 2 + 1];
        colsml[c][0] = b1[c] + u0 * W1[c] + u1 * W1[256 + c];
        colsml[c][1] = W1[512 + c];
        colsml[c][2] = W1[768 + c];
        colsml[c][3] = W1[1024 + c];
        colsml[c][4] = W1[1280 + c];
        colsml[c][5] = W1[1536 + c];
        colsml[c][6] = b2[c];
        if (c < 128) colsml[c][7] = b3[c];
    }
    if (t < 64) {
        rowsml[t][0] = sqrtf(ax * ax + ay * ay + az * az);  // lane==t here
#pragma unroll
        for (int p = 0; p < 4; ++p) {
            const float* bp = basis + (b * 4 + p) * 3;
            rowsml[t][1 + p] = ax * bp[0] + ay * bp[1] + az * bp[2];
        }
    }

    // swizzled LDS addressing (all loop-invariant); conflict-free (r2/r3)
    char* aswp = Asb + lane * 128 + ((w ^ (lane & 7)) << 4);   // write ptr, buf0
    int ro[4];
    {
        int sl = (lq ^ (lr & 7));
#pragma unroll
        for (int i = 0; i < 4; ++i)
            ro[i] = (i * 16 + lr) * 128 + (sl << 4);           // kk=0; kk=1 is ^64
    }

    // ---- gen split (T14): load stage (uniform scalar-path, issued early)
    struct XR { float4 x0, x1, y0, y1, z0, z1; };
    auto gen_load = [&](int s) {
        int c0u = __builtin_amdgcn_readfirstlane(s * 64 + w * 8);
        const float* Xc = Xg + c0u;
        XR r;
        r.x0 = *(const float4*)(Xc);        r.x1 = *(const float4*)(Xc + 4);
        r.y0 = *(const float4*)(Xc + 2048); r.y1 = *(const float4*)(Xc + 2052);
        r.z0 = *(const float4*)(Xc + 4096); r.z1 = *(const float4*)(Xc + 4100);
        return r;
    };
    // compute+store stage: 8 dots from staged regs -> As ring buf (swizzled b128)
    auto gen_cs = [&](const XR& rg, int buf) {
        v2f dA, dB, dC, dD;
        {
            v2f t0 = {rg.x0.x, rg.x0.y}, t1 = {rg.x0.z, rg.x0.w};
            v2f t2 = {rg.x1.x, rg.x1.y}, t3 = {rg.x1.z, rg.x1.w};
            dA = t0 * ax; dB = t1 * ax; dC = t2 * ax; dD = t3 * ax;
        }
        {
            v2f t0 = {rg.y0.x, rg.y0.y}, t1 = {rg.y0.z, rg.y0.w};
            v2f t2 = {rg.y1.x, rg.y1.y}, t3 = {rg.y1.z, rg.y1.w};
            dA += t0 * ay; dB += t1 * ay; dC += t2 * ay; dD += t3 * ay;
        }
        {
            v2f t0 = {rg.z0.x, rg.z0.y}, t1 = {rg.z0.z, rg.z0.w};
            v2f t2 = {rg.z1.x, rg.z1.y}, t3 = {rg.z1.z, rg.z1.w};
            dA += t0 * az; dB += t1 * az; dC += t2 * az; dD += t3 * az;
        }
        float s0 = __builtin_amdgcn_sqrtf(dA.x);
        float s1 = __builtin_amdgcn_sqrtf(dA.y);
        float s2 = __builtin_amdgcn_sqrtf(dB.x);
        float s3 = __builtin_amdgcn_sqrtf(dB.y);
        float s4 = __builtin_amdgcn_sqrtf(dC.x);
        float s5 = __builtin_amdgcn_sqrtf(dC.y);
        float s6 = __builtin_amdgcn_sqrtf(dD.x);
        float s7 = __builtin_amdgcn_sqrtf(dD.y);
        uint4 dv;
        dv.x = pack2bf(s0, s1); dv.y = pack2bf(s2, s3);
        dv.z = pack2bf(s4, s5); dv.w = pack2bf(s6, s7);
        *(uint4*)(aswp + buf * 8192) = dv;
    };

    floatx4 acc[4][2];
    const floatx4 zero = {0.f, 0.f, 0.f, 0.f};
#pragma unroll
    for (int i = 0; i < 4; ++i)
#pragma unroll
        for (int j = 0; j < 2; ++j) acc[i][j] = zero;

    // prologue: fill ring bufs 0,1 inline; stage loads for ss 2
    {
        XR r0 = gen_load(0);
        gen_cs(r0, 0);
        XR r1 = gen_load(1);
        gen_cs(r1, 1);
    }
    XR R = gen_load(2);
    __syncthreads();

    {
        const u16* wf = W1frag + t * 16;
        short8 a[4], bfr[4];
#pragma unroll 2
        for (int s = 0; s < 32; ++s) {
            const int buf = s & 3;
            const u16* wb = wf + (2 * s) * 8192;   // L2-hot B stream
            bfr[0] = *(const short8*)(wb);
            bfr[1] = *(const short8*)(wb + 8);
            bfr[2] = *(const short8*)(wb + 8192);
            bfr[3] = *(const short8*)(wb + 8192 + 8);
            // A kk=0
#pragma unroll
            for (int i = 0; i < 4; ++i)
                a[i] = *(const short8*)(Asb + buf * 8192 + ro[i]);
            // dots for s+2 from regs staged at s-1; then issue loads for s+3
            if (s < 30) gen_cs(R, (s + 2) & 3);
            if (s < 29) R = gen_load(s + 3);
#pragma unroll
            for (int i = 0; i < 4; ++i)
#pragma unroll
                for (int j = 0; j < 2; ++j)
                    acc[i][j] = mfma16(a[i], bfr[j], acc[i][j]);
            // A kk=1 (same buffer; reads hide under other waves' MFMA issue)
#pragma unroll
            for (int i = 0; i < 4; ++i)
                a[i] = *(const short8*)(Asb + buf * 8192 + (ro[i] ^ 64));
#pragma unroll
            for (int i = 0; i < 4; ++i)
#pragma unroll
                for (int j = 0; j < 2; ++j)
                    acc[i][j] = mfma16(a[i], bfr[2 + j], acc[i][j]);
            if (s & 1) __syncthreads();            // one barrier per 2 supersteps
        }
    }

    // ---- epilogue: h1 = small features + bias, LeakyReLU -> h1s (LDS bf16)
    // Ring is dead now (last ss=31 is odd -> ended with a barrier); overlays OK.
    if (t < 64) { xsm[t][0] = ax; xsm[t][1] = ay; xsm[t][2] = az; }
    const int c0 = w * 32 + lr, c1 = c0 + 16;
    const int c3 = w * 16 + lr;
    float cb0, cb1, cb3;   // b2/b3 pulled from colsml BEFORE h2s overwrites it
    {
        float c0v[7], c1v[7];
#pragma unroll
        for (int q = 0; q < 7; ++q) { c0v[q] = colsml[c0][q]; c1v[q] = colsml[c1][q]; }
        cb0 = c0v[6]; cb1 = c1v[6];
        cb3 = colsml[c3][7];
#pragma unroll
        for (int i = 0; i < 4; ++i) {
#pragma unroll
            for (int r = 0; r < 4; ++r) {
                int row = i * 16 + lq * 4 + r;
                float nrm = rowsml[row][0];
                float p0 = rowsml[row][1], p1 = rowsml[row][2];
                float p2 = rowsml[row][3], p3 = rowsml[row][4];
                float v0 = acc[i][0][r] + c0v[0] + nrm * c0v[1] +
                           p0 * c0v[2] + p1 * c0v[3] + p2 * c0v[4] + p3 * c0v[5];
                v0 = v0 > 0.f ? v0 : 0.01f * v0;
                h1s[row][c0] = f2bf(v0);
                float v1 = acc[i][1][r] + c1v[0] + nrm * c1v[1] +
                           p0 * c1v[2] + p1 * c1v[3] + p2 * c1v[4] + p3 * c1v[5];
                v1 = v1 > 0.f ? v1 : 0.01f * v1;
                h1s[row][c1] = f2bf(v1);
            }
        }
    }
    __syncthreads();

    // ---- phase 1: h2 = lrelu(h1s @ W2 + b2) -> h2s (overwrites colsml; safe)
#pragma unroll
    for (int i = 0; i < 4; ++i)
#pragma unroll
        for (int j = 0; j < 2; ++j) acc[i][j] = zero;
    {
        const u16* w2s = W2frag + t * 16;
#pragma unroll 2
        for (int kt = 0; kt < 8; ++kt) {
            short8 af[4], bfr[2];
#pragma unroll
            for (int i = 0; i < 4; ++i)
                af[i] = *(const short8*)&h1s[i * 16 + lr][kt * 32 + lq * 8];
#pragma unroll
            for (int j = 0; j < 2; ++j)
                bfr[j] = *(const short8*)(w2s + kt * 8192 + j * 8);
#pragma unroll
            for (int i = 0; i < 4; ++i)
#pragma unroll
                for (int j = 0; j < 2; ++j)
                    acc[i][j] = mfma16(af[i], bfr[j], acc[i][j]);
        }
#pragma unroll
        for (int i = 0; i < 4; ++i)
#pragma unroll
            for (int r = 0; r < 4; ++r) {
                int row = i * 16 + lq * 4 + r;
                float v0 = acc[i][0][r] + cb0;
                v0 = v0 > 0.f ? v0 : 0.01f * v0;
                h2s[row][c0] = f2bf(v0);
                float v1 = acc[i][1][r] + cb1;
                v1 = v1 > 0.f ? v1 : 0.01f * v1;
                h2s[row][c1] = f2bf(v1);
            }
    }
    __syncthreads();

    // ---- phase 2: fk = h2s @ W3 + b3, fused x outer-product reduce
    {
        floatx4 acc2[4];
#pragma unroll
        for (int i = 0; i < 4; ++i) acc2[i] = zero;
        const u16* w3s = W3frag + t * 8;
#pragma unroll 2
        for (int kt = 0; kt < 8; ++kt) {
            short8 af[4];
#pragma unroll
            for (int i = 0; i < 4; ++i)
                af[i] = *(const short8*)&h2s[i * 16 + lr][kt * 32 + lq * 8];
            short8 bfr = *(const short8*)(w3s + kt * 4096);
#pragma unroll
            for (int i = 0; i < 4; ++i) acc2[i] = mfma16(af[i], bfr, acc2[i]);
        }
        float s0 = 0.f, s1 = 0.f, s2 = 0.f;
#pragma unroll
        for (int i = 0; i < 4; ++i)
#pragma unroll
            for (int r = 0; r < 4; ++r) {
                int row = i * 16 + lq * 4 + r;
                float fk = acc2[i][r] + cb3;
                s0 += fk * xsm[row][0];
                s1 += fk * xsm[row][1];
                s2 += fk * xsm[row][2];
            }
        s0 += __shfl_xor(s0, 16); s0 += __shfl_xor(s0, 32);
        s1 += __shfl_xor(s1, 16); s1 += __shfl_xor(s1, 32);
        s2 += __shfl_xor(s2, 16); s2 += __shfl_xor(s2, 32);
        if (lq == 0) {  // lanes 0..15; cols wave-exclusive
            redm[c3][0] = s0; redm[c3][1] = s1; redm[c3][2] = s2;
        }
    }
    __syncthreads();
    if (t < 128) {
#pragma unroll
        for (int d = 0; d < 3; ++d)
            atomicAdd(&out[(b * 128 + t) * 3 + d], redm[t][d] * (1.0f / 2048.0f));
    }
}

extern "C" void kernel_launch(void* const* d_in, const int* in_sizes, int n_in,
                              void* d_out, int out_size, void* d_ws, size_t ws_size,
                              hipStream_t stream) {
    const float* x     = (const float*)d_in[0];
    const float* u     = (const float*)d_in[1];
    const float* basis = (const float*)d_in[2];
    const float* W1    = (const float*)d_in[3];
    const float* b1    = (const float*)d_in[4];
    const float* W2    = (const float*)d_in[5];
    const float* b2    = (const float*)d_in[6];
    const float* W3    = (const float*)d_in[7];
    const float* b3    = (const float*)d_in[8];
    float* out = (float*)d_out;

    char* ws = (char*)d_ws;
    u16*  W1frag = (u16*)ws;                      // 1,048,576 B
    u16*  W2frag = (u16*)(ws + 1048576);          //   131,072 B
    u16*  W3frag = (u16*)(ws + 1179648);          //    65,536 B
    float* xsoa  = (float*)(ws + 1245184);        //   393,216 B

    k_prep<<<2816, 256, 0, stream>>>(x, W1, W2, W3, xsoa, W1frag, W2frag,
                                     W3frag, out);
    k_fused<<<dim3(32, 16), 512, 0, stream>>>(xsoa, u, basis, W1, b1, b2, b3,
                                              W1frag, W2frag, W3frag, out);
}